// Round 8
// baseline (574.270 us; speedup 1.0000x reference)
//
#include <hip/hip_runtime.h>
#include <math.h>

#define K_DIM 256
#define BJ 128      // queries per block (B-tile fully resident in LDS)
#define SLICES 16   // grid (96,16,2)=3072 blocks of 256 thr, 2/CU resident

typedef unsigned long long u64;
typedef __attribute__((ext_vector_type(8))) short bf16x8;   // MFMA A/B frag (4 VGPR)
typedef __attribute__((ext_vector_type(4))) float f32x4;    // MFMA C/D frag

// Monotone map fp32 -> u32 so unsigned compare == float compare.
__device__ __forceinline__ u64 packKey(float v, unsigned idx) {
    unsigned u = __float_as_uint(v);
    u = (u & 0x80000000u) ? ~u : (u | 0x80000000u);
    return ((u64)u << 32) | idx;
}
__device__ __forceinline__ float unpackVal(u64 k) {
    unsigned u = (unsigned)(k >> 32);
    u = (u & 0x80000000u) ? (u ^ 0x80000000u) : ~u;
    return __uint_as_float(u);
}
__device__ __forceinline__ u64 shfl_xor_u64(u64 x, int m) {
    unsigned lo = (unsigned)x, hi = (unsigned)(x >> 32);
    lo = __shfl_xor(lo, m, 64);
    hi = __shfl_xor(hi, m, 64);
    return ((u64)hi << 32) | lo;
}

__device__ __forceinline__ unsigned short f2bf(float x) {   // RNE fp32->bf16
    unsigned u = __float_as_uint(x);
    return (unsigned short)((u + 0x7FFFu + ((u >> 16) & 1u)) >> 16);
}
__device__ __forceinline__ float bf2f(unsigned short b) {
    return __uint_as_float((unsigned)b << 16);
}

// Packed fragment layout (per tensor): PK[c][i16][lane][j] shorts, where
// c = k-chunk (k = 32c + 8*(lane>>4) + j), i16 = row/16, row = 16*i16 +
// (lane&15), j in [0,8). One (c,i16) cell = 64 lanes x 16 B = 1 KB = one
// MFMA operand fragment (A and B operand layouts are identical for
// 16x16x32, so one packing serves both sides).

// One wave per row: quantize fp32->bf16 into PACKED layout, compute the
// norm of the QUANTIZED vector, init min-key arrays + output.
__global__ void convert_kernel(const float* __restrict__ real, const float* __restrict__ gen,
                               short* __restrict__ realP, short* __restrict__ genP,
                               float* __restrict__ rn, float* __restrict__ gn,
                               u64* __restrict__ realKey, u64* __restrict__ genKey,
                               float* __restrict__ out, int N, int M) {
    int wv = (blockIdx.x * blockDim.x + threadIdx.x) >> 6;
    int lane = threadIdx.x & 63;
    if (wv >= N + M) return;
    const float* src;
    short* dstP;
    int r, NT;
    if (wv < N) { src = real + (size_t)wv * K_DIM; dstP = realP; r = wv; NT = N >> 4; }
    else        { src = gen + (size_t)(wv - N) * K_DIM; dstP = genP; r = wv - N; NT = M >> 4; }
    float4 v = ((const float4*)src)[lane];   // k = 4*lane .. 4*lane+3
    ushort4 b;
    b.x = f2bf(v.x); b.y = f2bf(v.y); b.z = f2bf(v.z); b.w = f2bf(v.w);
    float qx = bf2f(b.x), qy = bf2f(b.y), qz = bf2f(b.z), qw = bf2f(b.w);
    float s = qx * qx + qy * qy + qz * qz + qw * qw;
    // dest: c = lane>>3, quad = (lane>>1)&3, byte group j0 = (lane&1)*4
    int c = lane >> 3;
    int lane_p = (r & 15) + (((lane >> 1) & 3) << 4);
    size_t sidx = (((size_t)c * NT + (r >> 4)) * 64 + lane_p) * 8 + (lane & 1) * 4;
    *(ushort4*)(dstP + sidx) = b;
    #pragma unroll
    for (int off = 32; off > 0; off >>= 1) s += __shfl_down(s, off, 64);
    if (lane == 0) {
        if (wv < N) { rn[wv] = s; realKey[wv] = ~0ull; }
        else        { gn[wv - N] = s; genKey[wv - N] = ~0ull; }
        if (wv == 0) out[0] = 0.f;
    }
}

// Fused bf16-MFMA GEMM + column-min(+argmin). blockIdx.z: 0 = real queries
// (diagonal excluded), 1 = gen queries. Min is over db rows (real).
//
// ONE-BARRIER structure: the full B-tile (128 queries x K=256 = 64 KB,
// packed frag order) is loaded into LDS once via global_load_lds; after a
// single __syncthreads the 4 waves FREE-RUN: each computes 3 sequential
// 64x128 A-tiles (4x8 frags of 16x16x32, acc = 128 VGPR), streaming A
// fragments from L2 with chunk-distance-2 register prefetch. Per-MFMA
// cost: 128 B global (L2-resident 384 KB A-slice shared by all same-y
// blocks) + 256 B LDS — both below pipe parity, leaving MFMA binding.
__global__ __launch_bounds__(256, 2) void nn_kernel(
    const short* __restrict__ realP, const short* __restrict__ genP,
    const float* __restrict__ rn,
    u64* __restrict__ realKey, u64* __restrict__ genKey,
    int N, int M) {

    const bool isReal = (blockIdx.z == 0);
    const short* __restrict__ qP = isReal ? realP : genP;
    u64* outKey = isReal ? realKey : genKey;

    const int j0 = blockIdx.x * BJ;
    const int rowsPerSlice = N / SLICES;          // 768
    const int r0 = blockIdx.y * rowsPerSlice;

    const size_t CSTEPA = (size_t)(N >> 4) * 1024;               // bytes / c-step
    const size_t CSTEPB = (size_t)((isReal ? N : M) >> 4) * 1024;

    __shared__ short Bt[BJ * K_DIM];   // 64 KB: [c][j16][lane][8] frag order
    __shared__ u64 red[BJ];            // 1 KB

    const int tid = threadIdx.x;
    const int lane = tid & 63;
    const int w = tid >> 6;            // 0..3
    const int quad = lane >> 4;
    const int col = lane & 15;

    // ---- Fill B-tile LDS (16 x 4 KB global_load_lds issues), 1 barrier ----
    {
        const char* bSrc = (const char*)qP + (size_t)(j0 >> 4) * 1024;
        #pragma unroll
        for (int i = 0; i < 16; ++i) {
            int c = i >> 1;
            int half = (i & 1) * 256;
            __builtin_amdgcn_global_load_lds(
                (const __attribute__((address_space(1))) void*)
                    (bSrc + (size_t)c * CSTEPB + (half + tid) * 16),
                (__attribute__((address_space(3))) void*)
                    (Bt + c * 4096 + (half + (tid & ~63)) * 8),
                16, 0, 0);
        }
    }
    if (tid < BJ) red[tid] = ~0ull;
    __syncthreads();   // the ONLY barrier before the final reduction

    const char* BtB = (const char*)Bt;
    const char* aBase = (const char*)realP + (size_t)lane * 16;

    float minv[8];
    int mini[8];
    #pragma unroll
    for (int ni = 0; ni < 8; ++ni) { minv[ni] = 3.4e38f; mini[ni] = 0; }

    for (int t = 0; t < 3; ++t) {
        const int Rt = r0 + (t * 4 + w) * 64;     // this wave's 64-row A-tile
        const char* aT = aBase + (size_t)(Rt >> 4) * 1024;

        f32x4 acc[4][8];
        #pragma unroll
        for (int mi = 0; mi < 4; ++mi)
            #pragma unroll
            for (int ni = 0; ni < 8; ++ni)
                acc[mi][ni] = (f32x4){0.f, 0.f, 0.f, 0.f};

        bf16x8 abuf[2][4];
        #pragma unroll
        for (int ri = 0; ri < 4; ++ri)
            abuf[0][ri] = *(const bf16x8*)(aT + ri * 1024);
        #pragma unroll
        for (int ri = 0; ri < 4; ++ri)
            abuf[1][ri] = *(const bf16x8*)(aT + CSTEPA + ri * 1024);

        #pragma unroll
        for (int c = 0; c < 8; ++c) {
            bf16x8 b[8];
            #pragma unroll
            for (int j = 0; j < 8; ++j)
                b[j] = *(const bf16x8*)(BtB + ((c * 8 + j) << 10) + lane * 16);
            #pragma unroll
            for (int mi = 0; mi < 4; ++mi)
                #pragma unroll
                for (int ni = 0; ni < 8; ++ni)
                    acc[mi][ni] = __builtin_amdgcn_mfma_f32_16x16x32_bf16(
                        abuf[c & 1][mi], b[ni], acc[mi][ni], 0, 0, 0);
            if (c < 6) {   // prefetch chunk c+2 into the buffer just consumed
                #pragma unroll
                for (int ri = 0; ri < 4; ++ri)
                    abuf[c & 1][ri] = *(const bf16x8*)(aT + (c + 2) * CSTEPA + ri * 1024);
            }
        }

        // Epilogue: v = rn[i] - 2*dot (qn[j] + sqrt deferred; monotone).
        // C/D layout: col = lane&15 (j), row = quad*4 + reg (i).
        float4 rnv4[4];
        #pragma unroll
        for (int mi = 0; mi < 4; ++mi)
            rnv4[mi] = *(const float4*)(rn + Rt + mi * 16 + quad * 4);
        #pragma unroll
        for (int ni = 0; ni < 8; ++ni) {
            int jg = j0 + ni * 16 + col;
            #pragma unroll
            for (int mi = 0; mi < 4; ++mi)
                #pragma unroll
                for (int r = 0; r < 4; ++r) {
                    int ig = Rt + mi * 16 + quad * 4 + r;
                    float v = (&rnv4[mi].x)[r] - 2.f * acc[mi][ni][r];
                    bool skip = isReal && (ig == jg);
                    if (!skip && v < minv[ni]) { minv[ni] = v; mini[ni] = ig; }
                }
        }
    }

    // Block reduction: cross-quad shuffle (lanes +-16/32 share a column),
    // LDS atomic merge of the 4 waves, one global atomic per column.
    #pragma unroll
    for (int ni = 0; ni < 8; ++ni) {
        u64 k = packKey(minv[ni], (unsigned)mini[ni]);
        u64 o = shfl_xor_u64(k, 16); if (o < k) k = o;
        o = shfl_xor_u64(k, 32); if (o < k) k = o;
        if (quad == 0) atomicMin(&red[ni * 16 + col], k);
    }
    __syncthreads();
    if (tid < BJ) atomicMin(&outKey[j0 + tid], red[tid]);
}

__global__ void finalize_kernel(const u64* __restrict__ realKey, const u64* __restrict__ genKey,
                                const float* __restrict__ rn, const float* __restrict__ gn,
                                float* __restrict__ out, int M) {
    int j = blockIdx.x * blockDim.x + threadIdx.x;
    float a = 0.f;
    if (j < M) {
        u64 gk = genKey[j];
        float mg = unpackVal(gk);
        int idx = (int)(gk & 0xFFFFFFFFu);
        float d1 = sqrtf(fmaxf(mg + gn[j], 0.f));
        u64 rk = realKey[idx];
        float d2 = sqrtf(fmaxf(unpackVal(rk) + rn[idx], 0.f));
        float z = (d2 - d1) * 10.f;   // / TEMP
        a = 1.f / (1.f + expf(-z));
    }
    #pragma unroll
    for (int off = 32; off > 0; off >>= 1) a += __shfl_down(a, off, 64);
    __shared__ float sred[4];
    int lane = threadIdx.x & 63, wv = threadIdx.x >> 6;
    if (lane == 0) sred[wv] = a;
    __syncthreads();
    if (threadIdx.x == 0) {
        float s = sred[0] + sred[1] + sred[2] + sred[3];
        atomicAdd(out, s * (-100.f / (float)M));
    }
}

extern "C" void kernel_launch(void* const* d_in, const int* in_sizes, int n_in,
                              void* d_out, int out_size, void* d_ws, size_t ws_size,
                              hipStream_t stream) {
    const float* real = (const float*)d_in[0];
    const float* gen  = (const float*)d_in[1];
    float* out = (float*)d_out;
    int N = in_sizes[0] / K_DIM;
    int M = in_sizes[1] / K_DIM;

    // Workspace layout (~12.9 MB total):
    u64* realKey = (u64*)d_ws;
    u64* genKey  = realKey + N;
    float* rn = (float*)(genKey + M);
    float* gn = rn + N;
    short* realP = (short*)(gn + M);
    short* genP  = realP + (size_t)N * K_DIM;

    int mx = (N > M ? N : M);
    convert_kernel<<<(N + M + 3) / 4, 256, 0, stream>>>(real, gen, realP, genP, rn, gn,
                                                        realKey, genKey, out, N, M);
    dim3 g((mx + BJ - 1) / BJ, SLICES, 2);
    nn_kernel<<<g, 256, 0, stream>>>(realP, genP, rn, realKey, genKey, N, M);
    finalize_kernel<<<(M + 255) / 256, 256, 0, stream>>>(realKey, genKey, rn, gn, out, M);
}

// Round 9
// 222.700 us; speedup vs baseline: 2.5787x; 2.5787x over previous
//
#include <hip/hip_runtime.h>
#include <math.h>

#define K_DIM 256
#define BJ 128      // queries per block (B-tile fully resident in LDS)
#define SLICES 16   // grid (96,16,2)=3072 blocks of 512 thr, 2/CU resident

typedef unsigned long long u64;
typedef __attribute__((ext_vector_type(8))) short bf16x8;   // MFMA A/B frag (4 VGPR)
typedef __attribute__((ext_vector_type(4))) float f32x4;    // MFMA C/D frag

// Monotone map fp32 -> u32 so unsigned compare == float compare.
__device__ __forceinline__ u64 packKey(float v, unsigned idx) {
    unsigned u = __float_as_uint(v);
    u = (u & 0x80000000u) ? ~u : (u | 0x80000000u);
    return ((u64)u << 32) | idx;
}
__device__ __forceinline__ float unpackVal(u64 k) {
    unsigned u = (unsigned)(k >> 32);
    u = (u & 0x80000000u) ? (u ^ 0x80000000u) : ~u;
    return __uint_as_float(u);
}
__device__ __forceinline__ u64 shfl_xor_u64(u64 x, int m) {
    unsigned lo = (unsigned)x, hi = (unsigned)(x >> 32);
    lo = __shfl_xor(lo, m, 64);
    hi = __shfl_xor(hi, m, 64);
    return ((u64)hi << 32) | lo;
}

__device__ __forceinline__ unsigned short f2bf(float x) {   // RNE fp32->bf16
    unsigned u = __float_as_uint(x);
    return (unsigned short)((u + 0x7FFFu + ((u >> 16) & 1u)) >> 16);
}
__device__ __forceinline__ float bf2f(unsigned short b) {
    return __uint_as_float((unsigned)b << 16);
}

// Packed fragment layout (per tensor): PK[c][i16][lane][j] shorts, where
// c = k-chunk (k = 32c + 8*(lane>>4) + j), i16 = row/16, row = 16*i16 +
// (lane&15), j in [0,8). One (c,i16) cell = 64 lanes x 16 B = 1 KB = one
// MFMA operand fragment (A and B operand layouts are identical for
// 16x16x32, so one packing serves both sides).

// One wave per row: quantize fp32->bf16 into PACKED layout, compute the
// norm of the QUANTIZED vector, init min-key arrays + output.
__global__ void convert_kernel(const float* __restrict__ real, const float* __restrict__ gen,
                               short* __restrict__ realP, short* __restrict__ genP,
                               float* __restrict__ rn, float* __restrict__ gn,
                               u64* __restrict__ realKey, u64* __restrict__ genKey,
                               float* __restrict__ out, int N, int M) {
    int wv = (blockIdx.x * blockDim.x + threadIdx.x) >> 6;
    int lane = threadIdx.x & 63;
    if (wv >= N + M) return;
    const float* src;
    short* dstP;
    int r, NT;
    if (wv < N) { src = real + (size_t)wv * K_DIM; dstP = realP; r = wv; NT = N >> 4; }
    else        { src = gen + (size_t)(wv - N) * K_DIM; dstP = genP; r = wv - N; NT = M >> 4; }
    float4 v = ((const float4*)src)[lane];   // k = 4*lane .. 4*lane+3
    ushort4 b;
    b.x = f2bf(v.x); b.y = f2bf(v.y); b.z = f2bf(v.z); b.w = f2bf(v.w);
    float qx = bf2f(b.x), qy = bf2f(b.y), qz = bf2f(b.z), qw = bf2f(b.w);
    float s = qx * qx + qy * qy + qz * qz + qw * qw;
    // dest: c = lane>>3, quad = (lane>>1)&3, byte group j0 = (lane&1)*4
    int c = lane >> 3;
    int lane_p = (r & 15) + (((lane >> 1) & 3) << 4);
    size_t sidx = (((size_t)c * NT + (r >> 4)) * 64 + lane_p) * 8 + (lane & 1) * 4;
    *(ushort4*)(dstP + sidx) = b;
    #pragma unroll
    for (int off = 32; off > 0; off >>= 1) s += __shfl_down(s, off, 64);
    if (lane == 0) {
        if (wv < N) { rn[wv] = s; realKey[wv] = ~0ull; }
        else        { gn[wv - N] = s; genKey[wv - N] = ~0ull; }
        if (wv == 0) out[0] = 0.f;
    }
}

// Fused bf16-MFMA GEMM + column-min(+argmin). blockIdx.z: 0 = real queries
// (diagonal excluded), 1 = gen queries. Min is over db rows (real).
//
// ONE-BARRIER structure, spill-proof geometry: full B-tile (128 x 256 =
// 64 KB packed frags) loaded to LDS once; after a single __syncthreads the
// 8 waves (4 wi x 2 wj) free-run over 6 A-tiles of 128 rows. Wave tile
// 32x64: acc = 2x4 frags = 32 VGPRs (R5-proven register shape — no spill),
// 2 A-frags/chunk streamed from global (L2-resident slice, ping-pong
// prefetch distance 1), 4 B-frags/chunk from LDS. No barriers in the hot
// loop -> per-wave partial vmcnt waits only.
__global__ __launch_bounds__(512, 4) void nn_kernel(
    const short* __restrict__ realP, const short* __restrict__ genP,
    const float* __restrict__ rn,
    u64* __restrict__ realKey, u64* __restrict__ genKey,
    int N, int M) {

    const bool isReal = (blockIdx.z == 0);
    const short* __restrict__ qP = isReal ? realP : genP;
    u64* outKey = isReal ? realKey : genKey;

    const int j0 = blockIdx.x * BJ;
    const int rowsPerSlice = N / SLICES;          // 768
    const int r0 = blockIdx.y * rowsPerSlice;
    const int iters = (rowsPerSlice / BJ) * 8;    // 6 tiles x 8 chunks = 48

    const size_t CSTEPA = (size_t)(N >> 4) * 1024;               // bytes / c-step
    const size_t CSTEPB = (size_t)((isReal ? N : M) >> 4) * 1024;

    __shared__ short Bt[BJ * K_DIM];   // 64 KB: [c][jcell][lane][8] frag order
    __shared__ u64 red[BJ];            // 1 KB

    const int tid = threadIdx.x;
    const int lane = tid & 63;
    const int w = tid >> 6;            // 0..7
    const int wi = w >> 1;             // wave's 32-row block (i): 0..3
    const int wj = w & 1;              // wave's 64-col block (j): 0..1
    const int quad = lane >> 4;
    const int col = lane & 15;

    // ---- Fill B-tile LDS: 8 rounds x 512 thr x 16 B; round p = chunk c=p,
    // jcell = tid>>6, dest cell p*8192 + (tid>>6)*1024 (+lane*16). --------
    {
        const char* bSrc = (const char*)qP + ((size_t)(j0 >> 4) + w) * 1024 + (size_t)lane * 16;
        char* bDst = (char*)Bt + w * 1024;
        #pragma unroll
        for (int p = 0; p < 8; ++p)
            __builtin_amdgcn_global_load_lds(
                (const __attribute__((address_space(1))) void*)(bSrc + (size_t)p * CSTEPB),
                (__attribute__((address_space(3))) void*)(bDst + p * 8192 - lane * 16),
                16, 0, 0);
    }
    if (tid < BJ) red[tid] = ~0ull;
    __syncthreads();   // the ONLY barrier before the final reduction

    // A fragment walker (R7-proven): start at row-cell (r0>>4)+wi*2,
    // chunk step +CSTEPA, tile step +8192B (128 rows) rewinding 7 chunks.
    const char* aP = (const char*)realP +
                     (((size_t)(r0 >> 4) + wi * 2) * 64 + lane) * 16;
    const char* BtB = (const char*)Bt + (size_t)wj * 4096 + (size_t)lane * 16;

    float minv[4];
    int mini[4];
    #pragma unroll
    for (int ni = 0; ni < 4; ++ni) { minv[ni] = 3.4e38f; mini[ni] = 0; }

    f32x4 acc[2][4];
    #pragma unroll
    for (int mi = 0; mi < 2; ++mi)
        #pragma unroll
        for (int ni = 0; ni < 4; ++ni)
            acc[mi][ni] = (f32x4){0.f, 0.f, 0.f, 0.f};

    auto loadA = [&](bf16x8* a) {
        a[0] = *(const bf16x8*)(aP);
        a[1] = *(const bf16x8*)(aP + 1024);
    };
    auto advance = [&](int it) {
        if ((it & 7) == 7) aP += 8192 - 7 * (ptrdiff_t)CSTEPA;
        else aP += CSTEPA;
    };
    auto mfmaAll = [&](const bf16x8* a, int it) {
        const char* bBase = BtB + (it & 7) * 8192;
        bf16x8 b[4];
        #pragma unroll
        for (int ni = 0; ni < 4; ++ni)
            b[ni] = *(const bf16x8*)(bBase + ni * 1024);
        #pragma unroll
        for (int mi = 0; mi < 2; ++mi)
            #pragma unroll
            for (int ni = 0; ni < 4; ++ni)
                acc[mi][ni] = __builtin_amdgcn_mfma_f32_16x16x32_bf16(a[mi], b[ni], acc[mi][ni], 0, 0, 0);
    };
    auto epilogue = [&](int Rt) {
        // v = rn[i] - 2*dot (qn[j] + sqrt deferred; monotone).
        // C/D layout: col = lane&15 (j), row = quad*4 + reg (i).
        float4 rnv4[2];
        #pragma unroll
        for (int mi = 0; mi < 2; ++mi)
            rnv4[mi] = *(const float4*)(rn + Rt + mi * 16 + quad * 4);
        #pragma unroll
        for (int ni = 0; ni < 4; ++ni) {
            int jg = j0 + wj * 64 + ni * 16 + col;
            #pragma unroll
            for (int mi = 0; mi < 2; ++mi)
                #pragma unroll
                for (int r = 0; r < 4; ++r) {
                    int ig = Rt + mi * 16 + quad * 4 + r;
                    float v = (&rnv4[mi].x)[r] - 2.f * acc[mi][ni][r];
                    bool skip = isReal && (ig == jg);
                    if (!skip && v < minv[ni]) { minv[ni] = v; mini[ni] = ig; }
                }
        }
        #pragma unroll
        for (int mi = 0; mi < 2; ++mi)
            #pragma unroll
            for (int ni = 0; ni < 4; ++ni)
                acc[mi][ni] = (f32x4){0.f, 0.f, 0.f, 0.f};
    };

    bf16x8 a0[2], a1[2];
    loadA(a0);
    advance(0);

    for (int it = 0; it < iters; it += 2) {
        loadA(a1);                      // prefetch it+1
        advance(it + 1);
        mfmaAll(a0, it);                // compute it (even: never a tile end)
        if (it + 2 < iters) {
            loadA(a0);                  // prefetch it+2
            advance(it + 2);
        }
        mfmaAll(a1, it + 1);            // compute it+1
        if (((it + 1) & 7) == 7)        // tile boundary
            epilogue(r0 + ((it + 1) >> 3) * BJ + wi * 32);
    }

    // Block reduction: cross-quad shuffle (lanes +-16/32 share a column),
    // LDS atomic merge of the wi waves, one global atomic per column.
    #pragma unroll
    for (int ni = 0; ni < 4; ++ni) {
        u64 k = packKey(minv[ni], (unsigned)mini[ni]);
        u64 o = shfl_xor_u64(k, 16); if (o < k) k = o;
        o = shfl_xor_u64(k, 32); if (o < k) k = o;
        if (quad == 0) atomicMin(&red[wj * 64 + ni * 16 + col], k);
    }
    __syncthreads();
    if (tid < BJ) atomicMin(&outKey[j0 + tid], red[tid]);
}

__global__ void finalize_kernel(const u64* __restrict__ realKey, const u64* __restrict__ genKey,
                                const float* __restrict__ rn, const float* __restrict__ gn,
                                float* __restrict__ out, int M) {
    int j = blockIdx.x * blockDim.x + threadIdx.x;
    float a = 0.f;
    if (j < M) {
        u64 gk = genKey[j];
        float mg = unpackVal(gk);
        int idx = (int)(gk & 0xFFFFFFFFu);
        float d1 = sqrtf(fmaxf(mg + gn[j], 0.f));
        u64 rk = realKey[idx];
        float d2 = sqrtf(fmaxf(unpackVal(rk) + rn[idx], 0.f));
        float z = (d2 - d1) * 10.f;   // / TEMP
        a = 1.f / (1.f + expf(-z));
    }
    #pragma unroll
    for (int off = 32; off > 0; off >>= 1) a += __shfl_down(a, off, 64);
    __shared__ float sred[4];
    int lane = threadIdx.x & 63, wv = threadIdx.x >> 6;
    if (lane == 0) sred[wv] = a;
    __syncthreads();
    if (threadIdx.x == 0) {
        float s = sred[0] + sred[1] + sred[2] + sred[3];
        atomicAdd(out, s * (-100.f / (float)M));
    }
}

extern "C" void kernel_launch(void* const* d_in, const int* in_sizes, int n_in,
                              void* d_out, int out_size, void* d_ws, size_t ws_size,
                              hipStream_t stream) {
    const float* real = (const float*)d_in[0];
    const float* gen  = (const float*)d_in[1];
    float* out = (float*)d_out;
    int N = in_sizes[0] / K_DIM;
    int M = in_sizes[1] / K_DIM;

    // Workspace layout (~12.9 MB total):
    u64* realKey = (u64*)d_ws;
    u64* genKey  = realKey + N;
    float* rn = (float*)(genKey + M);
    float* gn = rn + N;
    short* realP = (short*)(gn + M);
    short* genP  = realP + (size_t)N * K_DIM;

    int mx = (N > M ? N : M);
    convert_kernel<<<(N + M + 3) / 4, 256, 0, stream>>>(real, gen, realP, genP, rn, gn,
                                                        realKey, genKey, out, N, M);
    dim3 g((mx + BJ - 1) / BJ, SLICES, 2);
    nn_kernel<<<g, 512, 0, stream>>>(realP, genP, rn, realKey, genKey, N, M);
    finalize_kernel<<<(M + 255) / 256, 256, 0, stream>>>(realKey, genKey, rn, gn, out, M);
}